// Round 4
// baseline (10434.788 us; speedup 1.0000x reference)
//
#include <hip/hip_runtime.h>
#include <hip/hip_fp16.h>

#define TCH 256
#define NCH 4

typedef __attribute__((ext_vector_type(8))) _Float16 half8;
typedef __attribute__((ext_vector_type(4))) float floatx4;

__device__ __forceinline__ float sigm(float x) {
  return __builtin_amdgcn_rcpf(1.f + __builtin_amdgcn_exp2f(x * -1.44269504f));
}
__device__ __forceinline__ float tanha(float x) {
  // tanh(x) = 1 - 2/(exp2(2x*log2e)+1); saturates correctly at +-inf
  return 1.f - 2.f * __builtin_amdgcn_rcpf(1.f + __builtin_amdgcn_exp2f(x * 2.88539009f));
}

// LDS-only barrier: orders LDS writes->reads across waves WITHOUT draining
// vmcnt (the compiler's __syncthreads emits s_waitcnt vmcnt(0) lgkmcnt(0),
// which would stall on all in-flight global loads/stores every step).
__device__ __forceinline__ void lds_barrier() {
  asm volatile("s_waitcnt lgkmcnt(0)" ::: "memory");
  __builtin_amdgcn_s_barrier();
  asm volatile("" ::: "memory");
}

// ---------------- GEMM: C[m,n] = A[m,:] . B[n,:]  (B row-major [N][K], fp32)
// A is f16 (or fp32 for MLP1), staged to LDS as f16; MFMA 16x16x32 f16.
// M = 32768 (chunk rows, m = b*TCH + t), tiles 128x128, BK=32.  (unchanged)
template<bool AF32, bool RELUB>
__global__ __launch_bounds__(256, 2) void gemm_k(
    const void* __restrict__ Ab, const float* __restrict__ Bw,
    const float* __restrict__ bias, __half* __restrict__ C,
    const int* __restrict__ length, int K, int KT, int N, int arst, int t0)
{
  int b = blockIdx.x >> 1;                  // 2 m-tiles (128 rows) per batch elem
  int tloc0 = (blockIdx.x & 1) << 7;
  if (t0 + tloc0 >= length[b]) return;      // whole tile beyond ragged length

  __shared__ half8 As[128][5];              // [row][k-group of 8], 40 f16/row (pad)
  __shared__ half8 Bs[128][5];

  int tid = threadIdx.x;
  int wave = tid >> 6, lane = tid & 63;
  int wm = (wave & 1) << 6, wn = (wave >> 1) << 6;
  int quad = lane >> 4, sub = lane & 15;
  int n0 = blockIdx.y << 7;

  floatx4 acc[4][4];
#pragma unroll
  for (int i = 0; i < 4; ++i)
#pragma unroll
    for (int j = 0; j < 4; ++j)
#pragma unroll
      for (int e = 0; e < 4; ++e) acc[i][j][e] = 0.f;

  size_t arowbase = (size_t)b * arst + tloc0;

  for (int kt = 0; kt < KT; ++kt) {
    int k0 = kt << 5;
#pragma unroll
    for (int pass = 0; pass < 2; ++pass) {
      int idx = tid + (pass << 8);
      int r = idx >> 2, c8 = (idx & 3) << 3;
      int kb = k0 + c8;
      // ---- A tile
      half8 v;
      if (AF32) {
        const float* src = (const float*)Ab + (arowbase + r) * K + kb;
        if (kb + 8 <= K) {
          float4 u0 = *(const float4*)(src);
          float4 u1 = *(const float4*)(src + 4);
          v[0] = (_Float16)u0.x; v[1] = (_Float16)u0.y; v[2] = (_Float16)u0.z; v[3] = (_Float16)u0.w;
          v[4] = (_Float16)u1.x; v[5] = (_Float16)u1.y; v[6] = (_Float16)u1.z; v[7] = (_Float16)u1.w;
        } else {
#pragma unroll
          for (int i = 0; i < 8; ++i) v[i] = (kb + i < K) ? (_Float16)src[i] : (_Float16)0.f;
        }
      } else {
        const __half* src = (const __half*)Ab + (arowbase + r) * K + kb;
        if (kb + 8 <= K) v = *(const half8*)src;
        else {
#pragma unroll
          for (int i = 0; i < 8; ++i) v[i] = (kb + i < K) ? *(const _Float16*)(src + i) : (_Float16)0.f;
        }
      }
      As[r][c8 >> 3] = v;
      // ---- B tile (always fp32 weights [N][K])
      const float* bsrc = Bw + (size_t)(n0 + r) * K + kb;
      half8 w;
      if (kb + 8 <= K) {
        float4 u0 = *(const float4*)(bsrc);
        float4 u1 = *(const float4*)(bsrc + 4);
        w[0] = (_Float16)u0.x; w[1] = (_Float16)u0.y; w[2] = (_Float16)u0.z; w[3] = (_Float16)u0.w;
        w[4] = (_Float16)u1.x; w[5] = (_Float16)u1.y; w[6] = (_Float16)u1.z; w[7] = (_Float16)u1.w;
      } else {
#pragma unroll
        for (int i = 0; i < 8; ++i) w[i] = (kb + i < K) ? (_Float16)bsrc[i] : (_Float16)0.f;
      }
      Bs[r][c8 >> 3] = w;
    }
    __syncthreads();
    half8 af[4], bfr[4];
#pragma unroll
    for (int i = 0; i < 4; ++i) {
      af[i] = As[wm + (i << 4) + sub][quad];
      bfr[i] = Bs[wn + (i << 4) + sub][quad];
    }
#pragma unroll
    for (int mt = 0; mt < 4; ++mt)
#pragma unroll
      for (int nt = 0; nt < 4; ++nt)
        acc[mt][nt] = __builtin_amdgcn_mfma_f32_16x16x32_f16(af[mt], bfr[nt], acc[mt][nt], 0, 0, 0);
    __syncthreads();
  }
  // epilogue: D layout col=lane&15 (n), row=quad*4+reg (m)  [m89-verified]
  size_t mrowbase = (size_t)blockIdx.x << 7;
#pragma unroll
  for (int nt = 0; nt < 4; ++nt) {
    int n = n0 + wn + (nt << 4) + sub;
    float bv = 0.f;
    if (RELUB) bv = bias[n];
#pragma unroll
    for (int mt = 0; mt < 4; ++mt) {
#pragma unroll
      for (int r4 = 0; r4 < 4; ++r4) {
        int m = wm + (mt << 4) + (quad << 2) + r4;
        float v = acc[mt][nt][r4] + bv;
        if (RELUB) v = fmaxf(v, 0.f);
        C[(mrowbase + m) * (size_t)N + n] = __float2half(v);
      }
    }
  }
}

// ---------------- pack W_hh [1024][256] f32 -> MFMA B-frag order f16.
// frag idx = (((hf*8+wq)*4+gate)*8+kc); lane (q=lane>>4, r=lane&15):
//   8 f16 = Whh[n = gate*256 + hf*128 + wq*16 + r][k = kc*32 + q*8 + e]
__global__ void pack_whh(const float* __restrict__ whh, __half* __restrict__ wpk)
{
  int idx = blockIdx.x;           // 512 = 2*8*4*8
  int lane = threadIdx.x;
  int kc = idx & 7, gt = (idx >> 3) & 3, w = (idx >> 5) & 7, hf = idx >> 8;
  int n = (gt << 8) + (hf << 7) + (w << 4) + (lane & 15);
  int k = (kc << 5) + ((lane >> 4) << 3);
  const float* src = whh + (size_t)n * 256 + k;
  half8 v;
#pragma unroll
  for (int e = 0; e < 8; ++e) v[e] = (_Float16)src[e];
  ((half8*)wpk)[((size_t)idx << 6) + lane] = v;
}

// ---------------- LSTM scan, MFMA version (v4).
// 16 WGs x 256 thr (4 waves, __launch_bounds__(256,1) -> 512 VGPR budget;
// W_hh half truly register-resident: 256 regs/thread in unified VGPR/AGPR).
// WG (g,hf): batches [16g,16g+16), gate-row half hf, full K=256.
// v4: (a) raw LDS-only barriers (no vmcnt drain per step); (b) xg loads
// software-pipelined one full step ahead; (c) VMEM issue order chosen so
// counted waits never drain younger traffic (publish -> spec pw -> xg ->
// LDS -> hout last).
__global__ __launch_bounds__(256, 1) void scan_mf(
    const __half* __restrict__ xg, const __half* __restrict__ wpk,
    const float* __restrict__ bih, const float* __restrict__ bhh,
    __half* __restrict__ hout, __half* __restrict__ hsave,
    float* __restrict__ csave, unsigned long long* __restrict__ exch,
    const int* __restrict__ length, int t0)
{
  int bid = blockIdx.x;
  int g = bid & 7, hf = bid >> 3;               // pair (g,0)<->(g,1) on same XCD
  int sid = (g << 1) | hf;                      // state index
  int tid = threadIdx.x;
  int w = tid >> 6, lane = tid & 63;
  int q = lane >> 4, r = lane & 15;

  int maxlen = 0;
#pragma unroll
  for (int i = 0; i < 16; ++i) maxlen = max(maxlen, length[(g << 4) + i]);
  int tend = min(t0 + TCH, maxlen);
  if (t0 >= tend) return;                       // uniform across both WGs of pair

  __shared__ __align__(16) unsigned short hfr[4096];   // [0,2048) own frags, [2048,4096) partner

  // ---- resident B fragments: 256 regs. slot s: 0..3 own-half kc, 4..7 partner.
  half8 bf[4][2][8];
  {
    const half8* wpb = (const half8*)wpk;
#pragma unroll
    for (int gt = 0; gt < 4; ++gt)
#pragma unroll
      for (int jj = 0; jj < 2; ++jj)
#pragma unroll
        for (int s = 0; s < 8; ++s) {
          int kc = (s < 4) ? ((hf << 2) + s) : (((1 - hf) << 2) + (s - 4));
          int fi = ((((hf << 3) + ((w << 1) | jj)) << 2) + gt) * 8 + kc;
          bf[gt][jj][s] = wpb[((size_t)fi << 6) + lane];
        }
  }

  float bsum[4][2];
#pragma unroll
  for (int gt = 0; gt < 4; ++gt)
#pragma unroll
    for (int jj = 0; jj < 2; ++jj) {
      int n = (gt << 8) + (hf << 7) + (((w << 1) | jj) << 4) + r;
      bsum[gt][jj] = bih[n] + bhh[n];
    }

  // xg base pointers per acc row rr (batch m = q*4+rr)
  const __half* xb[4];
#pragma unroll
  for (int rr = 0; rr < 4; ++rr)
    xb[rr] = xg + ((size_t)((g << 4) + (q << 2) + rr) * TCH) * 1024
             + (hf << 7) + (w << 5) + r;

  float c0[2][4];
  if (t0 == 0) {
    ((uint4*)hfr)[tid] = uint4{0, 0, 0, 0};            // own region 4KB
    ((uint4*)hfr)[256 + tid] = uint4{0, 0, 0, 0};      // partner region 4KB
#pragma unroll
    for (int jj = 0; jj < 2; ++jj)
#pragma unroll
      for (int rr = 0; rr < 4; ++rr) c0[jj][rr] = 0.f;
  } else {
    ((uint4*)hfr)[tid] = ((const uint4*)(hsave + ((size_t)sid << 11)))[tid];
    ((uint4*)hfr)[256 + tid] = ((const uint4*)(hsave + ((size_t)(sid ^ 1) << 11)))[tid];
#pragma unroll
    for (int jj = 0; jj < 2; ++jj)
#pragma unroll
      for (int rr = 0; rr < 4; ++rr) {
        int i = (((w << 1) | jj) << 4) + r;
        c0[jj][rr] = csave[((size_t)sid << 11) + (i << 4) + (q << 2) + rr];
      }
  }
  __syncthreads();

  unsigned long long* exA = exch + ((size_t)sid << 11);          // 2 parities x 1024
  const unsigned long long* exB = exch + ((size_t)(sid ^ 1) << 11);

  unsigned* h1w = (unsigned*)hfr;             // own region as u32
  unsigned* h2w = (unsigned*)(hfr + 2048);    // partner region as u32
  // consumer mapping: this thread owns exchange words widx = tid*4 + j
  int m_c = tid >> 4;
  int pbase = (tid & 15) << 2;
  unsigned cuoff = ((((pbase >> 4) << 6) + (((pbase & 15) >> 2) << 4) + m_c) << 2);

  unsigned long long pw[4];
  int tendl = tend - t0;

  // prologue: xg loads for t0 (consumed at nonlinearity of step t0)
  __half xh[4][2][4];
#pragma unroll
  for (int gt = 0; gt < 4; ++gt)
#pragma unroll
    for (int jj = 0; jj < 2; ++jj)
#pragma unroll
      for (int rr = 0; rr < 4; ++rr)
        xh[gt][jj][rr] = xb[rr][(gt << 8) + (jj << 4)];

  for (int t = t0; t < tend; ++t) {
    int tl = t - t0;
    // own-half A frags (h_t)
    half8 afo[4];
#pragma unroll
    for (int s = 0; s < 4; ++s)
      afo[s] = *(const half8*)&hfr[((s << 6) + lane) << 3];

    floatx4 acc[4][2];
#pragma unroll
    for (int gt = 0; gt < 4; ++gt)
#pragma unroll
      for (int jj = 0; jj < 2; ++jj)
#pragma unroll
        for (int e = 0; e < 4; ++e) acc[gt][jj][e] = bsum[gt][jj];

    // MFMA own half (exchange latency hides under this phase)
#pragma unroll
    for (int s = 0; s < 4; ++s)
#pragma unroll
      for (int gt = 0; gt < 4; ++gt)
#pragma unroll
        for (int jj = 0; jj < 2; ++jj)
          acc[gt][jj] = __builtin_amdgcn_mfma_f32_16x16x32_f16(afo[s], bf[gt][jj][s], acc[gt][jj], 0, 0, 0);

    // validate speculative partner words (tag t), scatter to partner LDS region
    if (tl > 0) {
      const unsigned long long* pb = exB + ((size_t)(t & 1) << 10) + (tid << 2);
      for (;;) {
        bool ok = true;
#pragma unroll
        for (int j = 0; j < 4; ++j)
          if ((int)(unsigned)(pw[j] >> 32) != t) ok = false;
        if (ok) break;
        __builtin_amdgcn_s_sleep(1);
#pragma unroll
        for (int j = 0; j < 4; ++j)
          pw[j] = __hip_atomic_load(pb + j, __ATOMIC_RELAXED, __HIP_MEMORY_SCOPE_AGENT);
      }
      *(uint4*)&h2w[cuoff] = uint4{(unsigned)pw[0], (unsigned)pw[1],
                                   (unsigned)pw[2], (unsigned)pw[3]};
    }
    lds_barrier();        // partner region now h_t (LDS-only: vmem stays in flight)

    half8 afp[4];
#pragma unroll
    for (int s = 0; s < 4; ++s)
      afp[s] = *(const half8*)&hfr[2048 + (((s << 6) + lane) << 3)];
#pragma unroll
    for (int s = 0; s < 4; ++s)
#pragma unroll
      for (int gt = 0; gt < 4; ++gt)
#pragma unroll
        for (int jj = 0; jj < 2; ++jj)
          acc[gt][jj] = __builtin_amdgcn_mfma_f32_16x16x32_f16(afp[s], bf[gt][jj][4 + s], acc[gt][jj], 0, 0, 0);

    // nonlinearity + state update (consumes xh loaded one step ago)
    unsigned prv[2][4];
    unsigned short hrv[2][4];
#pragma unroll
    for (int jj = 0; jj < 2; ++jj)
#pragma unroll
      for (int rr = 0; rr < 4; ++rr) {
        float iv = sigm(acc[0][jj][rr] + __half2float(xh[0][jj][rr]));
        float fv = sigm(acc[1][jj][rr] + __half2float(xh[1][jj][rr]));
        float gv = tanha(acc[2][jj][rr] + __half2float(xh[2][jj][rr]));
        float ov = sigm(acc[3][jj][rr] + __half2float(xh[3][jj][rr]));
        float c = fmaf(fv, c0[jj][rr], iv * gv);
        c0[jj][rr] = c;
        float hv = ov * tanha(c);
        __half hh = __float2half(hv);
        hrv[jj][rr] = __half_as_ushort(hh);
        unsigned hu = (unsigned)hrv[jj][rr];
        unsigned ot = (unsigned)__shfl_xor((int)hu, 1);
        prv[jj][rr] = (ot << 16) | hu;      // valid on even-r lanes
      }

    // 1) publish exchange words (oldest vmem of the next window)
    if (!(r & 1)) {
      unsigned long long tg = ((unsigned long long)(unsigned)(t + 1)) << 32;
      unsigned long long* dstb = exA + ((size_t)((t + 1) & 1) << 10);
#pragma unroll
      for (int jj = 0; jj < 2; ++jj)
#pragma unroll
        for (int rr = 0; rr < 4; ++rr) {
          int m = (q << 2) + rr;
          int widx = (m << 6) + (((w << 1) | jj) << 3) + (r >> 1);
          __hip_atomic_store(dstb + widx, tg | (unsigned long long)prv[jj][rr],
                             __ATOMIC_RELAXED, __HIP_MEMORY_SCOPE_AGENT);
        }
    }
    // 2) speculative partner loads for step t+1
    if (t + 1 < tend) {
      const unsigned long long* pb = exB + ((size_t)((t + 1) & 1) << 10) + (tid << 2);
#pragma unroll
      for (int j = 0; j < 4; ++j)
        pw[j] = __hip_atomic_load(pb + j, __ATOMIC_RELAXED, __HIP_MEMORY_SCOPE_AGENT);
    }
    // 3) xg loads for step t+1 (full-step latency cover)
    {
      int tn = min(tl + 1, tendl - 1);
#pragma unroll
      for (int gt = 0; gt < 4; ++gt)
#pragma unroll
        for (int jj = 0; jj < 2; ++jj)
#pragma unroll
          for (int rr = 0; rr < 4; ++rr)
            xh[gt][jj][rr] = xb[rr][((size_t)tn << 10) + (gt << 8) + (jj << 4)];
    }
    // 4) own-frag LDS writes (h_{t+1})
    if (!(r & 1)) {
#pragma unroll
      for (int jj = 0; jj < 2; ++jj)
#pragma unroll
        for (int rr = 0; rr < 4; ++rr) {
          int m = (q << 2) + rr;
          h1w[(((w << 6) + ((((jj << 1) | (r >> 3))) << 4) + m) << 2) | ((r & 7) >> 1)] = prv[jj][rr];
        }
    }
    // 5) hout stores (youngest: never waited on)
#pragma unroll
    for (int jj = 0; jj < 2; ++jj)
#pragma unroll
      for (int rr = 0; rr < 4; ++rr) {
        int m = (q << 2) + rr;
        hout[((size_t)(((g << 4) + m) * TCH + tl) << 8) + (hf << 7) + (((w << 1) | jj) << 4) + r] =
            __ushort_as_half(hrv[jj][rr]);
      }
    lds_barrier();        // own-frag region now h_{t+1}
  }

  // carry state across chunks
  ((uint4*)(hsave + ((size_t)sid << 11)))[tid] = ((const uint4*)hfr)[tid];
#pragma unroll
  for (int jj = 0; jj < 2; ++jj)
#pragma unroll
    for (int rr = 0; rr < 4; ++rr) {
      int i = (((w << 1) | jj) << 4) + r;
      csave[((size_t)sid << 11) + (i << 4) + (q << 2) + rr] = c0[jj][rr];
    }
}

// ---------------- head: decision = h2 . Wd + bd, ragged-masked sum, final /len
__global__ __launch_bounds__(256, 2) void head_k(
    const __half* __restrict__ h2, const float* __restrict__ Wd,
    const float* __restrict__ bd, const int* __restrict__ length,
    float* __restrict__ dacc, float* __restrict__ out, int t0, int first, int last)
{
  int b = blockIdx.x, tid = threadIdx.x;
  int lane = tid & 63, wave = tid >> 6;
  int len = length[b];
  int tend = min(t0 + TCH, len);
  float4 w4 = *(const float4*)(Wd + (lane << 2));
  float wsum = 0.f;
  for (int t = t0 + wave; t < tend; t += 4) {
    const __half* hr = h2 + (((size_t)b * TCH) + (t - t0)) * 256 + (lane << 2);
    uint2 u = *(const uint2*)hr;
    __half2 p0 = __builtin_bit_cast(__half2, u.x);
    __half2 p1 = __builtin_bit_cast(__half2, u.y);
    float s = w4.x * __half2float(p0.x) + w4.y * __half2float(p0.y)
            + w4.z * __half2float(p1.x) + w4.w * __half2float(p1.y);
#pragma unroll
    for (int off = 32; off > 0; off >>= 1) s += __shfl_xor(s, off);
    wsum += s;    // s is full-wave sum, counted once via lane0 below
  }
  __shared__ float wred[4];
  if (lane == 0) wred[wave] = wsum;
  __syncthreads();
  if (tid == 0) {
    int cnt = tend - t0; if (cnt < 0) cnt = 0;
    float tot = wred[0] + wred[1] + wred[2] + wred[3] + bd[0] * (float)cnt;
    if (!first) tot += dacc[b];
    dacc[b] = tot;
    if (last) out[b] = tot / (float)len;
  }
}

extern "C" void kernel_launch(void* const* d_in, const int* in_sizes, int n_in,
                              void* d_out, int out_size, void* d_ws, size_t ws_size,
                              hipStream_t stream) {
  (void)in_sizes; (void)n_in; (void)out_size; (void)ws_size;
  const float* x    = (const float*)d_in[0];
  const int* length = (const int*)d_in[1];
  const float* W1   = (const float*)d_in[2];
  const float* b1   = (const float*)d_in[3];
  const float* W2   = (const float*)d_in[4];
  const float* b2   = (const float*)d_in[5];
  const float* wih[3] = {(const float*)d_in[6],  (const float*)d_in[10], (const float*)d_in[14]};
  const float* whh[3] = {(const float*)d_in[7],  (const float*)d_in[11], (const float*)d_in[15]};
  const float* bih[3] = {(const float*)d_in[8],  (const float*)d_in[12], (const float*)d_in[16]};
  const float* bhh[3] = {(const float*)d_in[9],  (const float*)d_in[13], (const float*)d_in[17]};
  const float* Wd   = (const float*)d_in[18];
  const float* bd   = (const float*)d_in[19];
  float* out = (float*)d_out;

  char* ws = (char*)d_ws;
  __half* XG    = (__half*)(ws);                     // 32768 x 1024 f16 = 64 MiB
  __half* FEAT2 = (__half*)(ws + 67108864);          // 32768 x 512  f16 = 32 MiB
  __half* FEAT1 = (__half*)(ws + 100663296);         // 32768 x 256  f16 = 16 MiB
  __half* HBUF  = FEAT1;                             // aliased: F1 dead before scan writes
  __half* WPK   = (__half*)(ws + 117440512);         // 3 x 512 KiB packed W_hh frags
  __half* HSV   = (__half*)(ws + 119013376);         // 3 x 64 KiB h state (frag order)
  float*  CSV   = (float*)(ws + 119209984);          // 3 x 128 KiB c state
  unsigned long long* EXC = (unsigned long long*)(ws + 119603200);  // 3 x 256 KiB exchange
  float* DACC   = (float*)(ws + 120389632);

  // pack recurrent weights into MFMA B-frag order (cheap, idempotent)
  for (int l = 0; l < 3; ++l)
    pack_whh<<<512, 64, 0, stream>>>(whh[l], WPK + (size_t)l * 262144);

  for (int c = 0; c < NCH; ++c) {
    int t0 = c * TCH;
    // MLP1: x[.,136] -> 256, relu
    gemm_k<true,  true ><<<dim3(256, 2), 256, 0, stream>>>(
        (const void*)(x + (size_t)t0 * 136), W1, b1, FEAT1, length, 136, 5, 256, 1024, t0);
    // MLP2: 256 -> 512, relu
    gemm_k<false, true ><<<dim3(256, 4), 256, 0, stream>>>(
        (const void*)FEAT1, W2, b2, FEAT2, length, 256, 8, 512, TCH, t0);
    // layer 0
    gemm_k<false, false><<<dim3(256, 8), 256, 0, stream>>>(
        (const void*)FEAT2, wih[0], nullptr, XG, length, 512, 16, 1024, TCH, t0);
    scan_mf<<<16, 256, 0, stream>>>(XG, WPK, bih[0], bhh[0], HBUF,
                                    HSV, CSV, EXC, length, t0);
    // layer 1
    gemm_k<false, false><<<dim3(256, 8), 256, 0, stream>>>(
        (const void*)HBUF, wih[1], nullptr, XG, length, 256, 8, 1024, TCH, t0);
    scan_mf<<<16, 256, 0, stream>>>(XG, WPK + 262144, bih[1], bhh[1], HBUF,
                                    HSV + 32768, CSV + 32768, EXC + 32768, length, t0);
    // layer 2
    gemm_k<false, false><<<dim3(256, 8), 256, 0, stream>>>(
        (const void*)HBUF, wih[2], nullptr, XG, length, 256, 8, 1024, TCH, t0);
    scan_mf<<<16, 256, 0, stream>>>(XG, WPK + 524288, bih[2], bhh[2], HBUF,
                                    HSV + 65536, CSV + 65536, EXC + 65536, length, t0);
    // head + ragged mean
    head_k<<<128, 256, 0, stream>>>(HBUF, Wd, bd, length, DACC, out, t0, c == 0, c == NCH - 1);
  }
}

// Round 7
// 7729.068 us; speedup vs baseline: 1.3501x; 1.3501x over previous
//
#include <hip/hip_runtime.h>
#include <hip/hip_fp16.h>

#define TCH 256
#define NCH 4

typedef __attribute__((ext_vector_type(8))) _Float16 half8;
typedef __attribute__((ext_vector_type(4))) float floatx4;

__device__ __forceinline__ float sigm(float x) {
  return __builtin_amdgcn_rcpf(1.f + __builtin_amdgcn_exp2f(x * -1.44269504f));
}
__device__ __forceinline__ float tanha(float x) {
  // tanh(x) = 1 - 2/(exp2(2x*log2e)+1); saturates correctly at +-inf
  return 1.f - 2.f * __builtin_amdgcn_rcpf(1.f + __builtin_amdgcn_exp2f(x * 2.88539009f));
}

// ---------------- GEMM: C[m,n] = A[m,:] . B[n,:]  (B row-major [N][K], fp32)
// A is f16 (or fp32 for MLP1), staged to LDS as f16; MFMA 16x16x32 f16.
// M = 32768 (chunk rows, m = b*TCH + t), tiles 128x128, BK=32.  (unchanged)
template<bool AF32, bool RELUB>
__global__ __launch_bounds__(256, 2) void gemm_k(
    const void* __restrict__ Ab, const float* __restrict__ Bw,
    const float* __restrict__ bias, __half* __restrict__ C,
    const int* __restrict__ length, int K, int KT, int N, int arst, int t0)
{
  int b = blockIdx.x >> 1;                  // 2 m-tiles (128 rows) per batch elem
  int tloc0 = (blockIdx.x & 1) << 7;
  if (t0 + tloc0 >= length[b]) return;      // whole tile beyond ragged length

  __shared__ half8 As[128][5];              // [row][k-group of 8], 40 f16/row (pad)
  __shared__ half8 Bs[128][5];

  int tid = threadIdx.x;
  int wave = tid >> 6, lane = tid & 63;
  int wm = (wave & 1) << 6, wn = (wave >> 1) << 6;
  int quad = lane >> 4, sub = lane & 15;
  int n0 = blockIdx.y << 7;

  floatx4 acc[4][4];
#pragma unroll
  for (int i = 0; i < 4; ++i)
#pragma unroll
    for (int j = 0; j < 4; ++j)
#pragma unroll
      for (int e = 0; e < 4; ++e) acc[i][j][e] = 0.f;

  size_t arowbase = (size_t)b * arst + tloc0;

  for (int kt = 0; kt < KT; ++kt) {
    int k0 = kt << 5;
#pragma unroll
    for (int pass = 0; pass < 2; ++pass) {
      int idx = tid + (pass << 8);
      int r = idx >> 2, c8 = (idx & 3) << 3;
      int kb = k0 + c8;
      // ---- A tile
      half8 v;
      if (AF32) {
        const float* src = (const float*)Ab + (arowbase + r) * K + kb;
        if (kb + 8 <= K) {
          float4 u0 = *(const float4*)(src);
          float4 u1 = *(const float4*)(src + 4);
          v[0] = (_Float16)u0.x; v[1] = (_Float16)u0.y; v[2] = (_Float16)u0.z; v[3] = (_Float16)u0.w;
          v[4] = (_Float16)u1.x; v[5] = (_Float16)u1.y; v[6] = (_Float16)u1.z; v[7] = (_Float16)u1.w;
        } else {
#pragma unroll
          for (int i = 0; i < 8; ++i) v[i] = (kb + i < K) ? (_Float16)src[i] : (_Float16)0.f;
        }
      } else {
        const __half* src = (const __half*)Ab + (arowbase + r) * K + kb;
        if (kb + 8 <= K) v = *(const half8*)src;
        else {
#pragma unroll
          for (int i = 0; i < 8; ++i) v[i] = (kb + i < K) ? *(const _Float16*)(src + i) : (_Float16)0.f;
        }
      }
      As[r][c8 >> 3] = v;
      // ---- B tile (always fp32 weights [N][K])
      const float* bsrc = Bw + (size_t)(n0 + r) * K + kb;
      half8 w;
      if (kb + 8 <= K) {
        float4 u0 = *(const float4*)(bsrc);
        float4 u1 = *(const float4*)(bsrc + 4);
        w[0] = (_Float16)u0.x; w[1] = (_Float16)u0.y; w[2] = (_Float16)u0.z; w[3] = (_Float16)u0.w;
        w[4] = (_Float16)u1.x; w[5] = (_Float16)u1.y; w[6] = (_Float16)u1.z; w[7] = (_Float16)u1.w;
      } else {
#pragma unroll
        for (int i = 0; i < 8; ++i) w[i] = (kb + i < K) ? (_Float16)bsrc[i] : (_Float16)0.f;
      }
      Bs[r][c8 >> 3] = w;
    }
    __syncthreads();
    half8 af[4], bfr[4];
#pragma unroll
    for (int i = 0; i < 4; ++i) {
      af[i] = As[wm + (i << 4) + sub][quad];
      bfr[i] = Bs[wn + (i << 4) + sub][quad];
    }
#pragma unroll
    for (int mt = 0; mt < 4; ++mt)
#pragma unroll
      for (int nt = 0; nt < 4; ++nt)
        acc[mt][nt] = __builtin_amdgcn_mfma_f32_16x16x32_f16(af[mt], bfr[nt], acc[mt][nt], 0, 0, 0);
    __syncthreads();
  }
  // epilogue: D layout col=lane&15 (n), row=quad*4+reg (m)  [m89-verified]
  size_t mrowbase = (size_t)blockIdx.x << 7;
#pragma unroll
  for (int nt = 0; nt < 4; ++nt) {
    int n = n0 + wn + (nt << 4) + sub;
    float bv = 0.f;
    if (RELUB) bv = bias[n];
#pragma unroll
    for (int mt = 0; mt < 4; ++mt) {
#pragma unroll
      for (int r4 = 0; r4 < 4; ++r4) {
        int m = wm + (mt << 4) + (quad << 2) + r4;
        float v = acc[mt][nt][r4] + bv;
        if (RELUB) v = fmaxf(v, 0.f);
        C[(mrowbase + m) * (size_t)N + n] = __float2half(v);
      }
    }
  }
}

// ---------------- pack W_hh [1024][256] f32 -> MFMA B-frag order f16.
// frag idx = (((hf*8+wq)*4+gate)*8+kc); lane (q=lane>>4, r=lane&15):
//   8 f16 = Whh[n = gate*256 + hf*128 + wq*16 + r][k = kc*32 + q*8 + e]
__global__ void pack_whh(const float* __restrict__ whh, __half* __restrict__ wpk)
{
  int idx = blockIdx.x;           // 512 = 2*8*4*8
  int lane = threadIdx.x;
  int kc = idx & 7, gt = (idx >> 3) & 3, w = (idx >> 5) & 7, hf = idx >> 8;
  int n = (gt << 8) + (hf << 7) + (w << 4) + (lane & 15);
  int k = (kc << 5) + ((lane >> 4) << 3);
  const float* src = whh + (size_t)n * 256 + k;
  half8 v;
#pragma unroll
  for (int e = 0; e < 8; ++e) v[e] = (_Float16)src[e];
  ((half8*)wpk)[((size_t)idx << 6) + lane] = v;
}

// ---------------- LSTM scan, MFMA version (v5b).
// 16 WGs x 512 thr (8 waves, 2 waves/SIMD -> each SIMD has a partner wave to
// issue during the other's stalls; round-4 counters showed ~65% stall at
// 1 wave/SIMD).  VGPR cap 256: weights 128 regs/thread (wave owns 16
// h-cols: 4 n-tiles x 8 kc = 32 MFMA/wave/step).
// WG (g,hf): batches [16g,16g+16), gate-row half hf, full K=256.
// Protocol/barriers identical to the verified round-3 version (__syncthreads,
// xh issued at iteration top, tagged u64 parity-dbuf exchange, spec loads).
// v5b: spin-wait BOUNDED (diagnostic safety valve — never reached in normal
// operation; on pathological stall the kernel completes instead of hanging
// the container, surfacing as absmax/dur anomaly we can diagnose).
__global__ __launch_bounds__(512, 2) void scan_mf(
    const __half* __restrict__ xg, const __half* __restrict__ wpk,
    const float* __restrict__ bih, const float* __restrict__ bhh,
    __half* __restrict__ hout, __half* __restrict__ hsave,
    float* __restrict__ csave, unsigned long long* __restrict__ exch,
    const int* __restrict__ length, int t0)
{
  int bid = blockIdx.x;
  int g = bid & 7, hf = bid >> 3;               // pair (g,0)<->(g,1), bid^8: same XCD
  int sid = (g << 1) | hf;                      // state index
  int tid = threadIdx.x;
  int w = tid >> 6, lane = tid & 63;            // w in 0..7
  int q = lane >> 4, r = lane & 15;

  int maxlen = 0;
#pragma unroll
  for (int i = 0; i < 16; ++i) maxlen = max(maxlen, length[(g << 4) + i]);
  int tend = min(t0 + TCH, maxlen);
  if (t0 >= tend) return;                       // uniform across both WGs of pair

  __shared__ __align__(16) unsigned short hfr[4096];   // [0,2048) own frags, [2048,4096) partner

  // ---- resident B fragments: 128 regs. slot s: 0..3 own-half kc, 4..7 partner.
  half8 bf[4][8];
  {
    const half8* wpb = (const half8*)wpk;
#pragma unroll
    for (int gt = 0; gt < 4; ++gt)
#pragma unroll
      for (int s = 0; s < 8; ++s) {
        int kc = (s < 4) ? ((hf << 2) + s) : (((1 - hf) << 2) + (s - 4));
        int fi = ((((hf << 3) + w) << 2) + gt) * 8 + kc;
        bf[gt][s] = wpb[((size_t)fi << 6) + lane];
      }
  }

  int nbase = (hf << 7) + (w << 4) + r;         // gate-row column for this thread
  float bsum[4];
#pragma unroll
  for (int gt = 0; gt < 4; ++gt) bsum[gt] = bih[(gt << 8) + nbase] + bhh[(gt << 8) + nbase];

  // xg base pointers per acc row rr (batch m = 4q+rr)
  const __half* xb[4];
#pragma unroll
  for (int rr = 0; rr < 4; ++rr)
    xb[rr] = xg + ((size_t)((g << 4) + (q << 2) + rr) * TCH) * 1024 + nbase;

  float c0[4];
  if (t0 == 0) {
    ((uint4*)hfr)[tid] = uint4{0, 0, 0, 0};     // 512 uint4 = both regions
#pragma unroll
    for (int rr = 0; rr < 4; ++rr) c0[rr] = 0.f;
  } else {
    if (tid < 256)
      ((uint4*)hfr)[tid] = ((const uint4*)(hsave + ((size_t)sid << 11)))[tid];
    else
      ((uint4*)hfr)[tid] = ((const uint4*)(hsave + ((size_t)(sid ^ 1) << 11)))[tid - 256];
    int i = (w << 4) + r;
#pragma unroll
    for (int rr = 0; rr < 4; ++rr)
      c0[rr] = csave[((size_t)sid << 11) + (i << 4) + (q << 2) + rr];
  }
  __syncthreads();

  unsigned long long* exA = exch + ((size_t)sid << 11);          // 2 parities x 1024
  const unsigned long long* exB = exch + ((size_t)(sid ^ 1) << 11);

  unsigned* h1w = (unsigned*)hfr;             // own region as u32
  unsigned* h2w = (unsigned*)(hfr + 2048);    // partner region as u32
  // consumer mapping: this thread owns exchange words widx = 2*tid, 2*tid+1
  int widx0 = tid << 1;
  int m_c = widx0 >> 6, p0 = widx0 & 63;
  unsigned cuoff = ((unsigned)(p0 >> 4) << 8) + ((unsigned)((p0 >> 2) & 3) << 6)
                 + ((unsigned)m_c << 2) + (unsigned)(p0 & 3);

  unsigned long long pw[2];

  for (int t = t0; t < tend; ++t) {
    int tl = t - t0;
    // own-half A frags (h_t)
    half8 afo[4];
#pragma unroll
    for (int s = 0; s < 4; ++s)
      afo[s] = *(const half8*)&hfr[((s << 6) + lane) << 3];

    // issue xg loads early (consumed at nonlinearity)
    __half xh[4][4];
#pragma unroll
    for (int gt = 0; gt < 4; ++gt)
#pragma unroll
      for (int rr = 0; rr < 4; ++rr)
        xh[gt][rr] = xb[rr][((size_t)tl << 10) + (gt << 8)];

    floatx4 acc[4];
#pragma unroll
    for (int gt = 0; gt < 4; ++gt)
#pragma unroll
      for (int e = 0; e < 4; ++e) acc[gt][e] = bsum[gt];

    // MFMA own half (exchange latency hides under this phase)
#pragma unroll
    for (int s = 0; s < 4; ++s)
#pragma unroll
      for (int gt = 0; gt < 4; ++gt)
        acc[gt] = __builtin_amdgcn_mfma_f32_16x16x32_f16(afo[s], bf[gt][s], acc[gt], 0, 0, 0);

    // validate speculative partner words (tag t), scatter to partner LDS region.
    // Spin is BOUNDED: guard never trips in normal operation (validation
    // usually succeeds on the speculative load); on pathological stall we
    // proceed (wrong data) rather than hang the container.
    if (tl > 0) {
      const unsigned long long* pb = exB + ((size_t)(t & 1) << 10) + widx0;
      int guard = 0;
      for (;;) {
        bool ok = ((int)(unsigned)(pw[0] >> 32) == t) &&
                  ((int)(unsigned)(pw[1] >> 32) == t);
        if (ok || ++guard > (1 << 20)) break;
        __builtin_amdgcn_s_sleep(1);
        pw[0] = __hip_atomic_load(pb, __ATOMIC_RELAXED, __HIP_MEMORY_SCOPE_AGENT);
        pw[1] = __hip_atomic_load(pb + 1, __ATOMIC_RELAXED, __HIP_MEMORY_SCOPE_AGENT);
      }
      *(uint2*)&h2w[cuoff] = uint2{(unsigned)pw[0], (unsigned)pw[1]};
    }
    __syncthreads();      // partner region now h_t

    half8 afp[4];
#pragma unroll
    for (int s = 0; s < 4; ++s)
      afp[s] = *(const half8*)&hfr[2048 + (((s << 6) + lane) << 3)];
#pragma unroll
    for (int s = 0; s < 4; ++s)
#pragma unroll
      for (int gt = 0; gt < 4; ++gt)
        acc[gt] = __builtin_amdgcn_mfma_f32_16x16x32_f16(afp[s], bf[gt][4 + s], acc[gt], 0, 0, 0);

    // nonlinearity + state update; pack h pairs in-register via shfl
    unsigned prv[4];
#pragma unroll
    for (int rr = 0; rr < 4; ++rr) {
      float iv = sigm(acc[0][rr] + __half2float(xh[0][rr]));
      float fv = sigm(acc[1][rr] + __half2float(xh[1][rr]));
      float gv = tanha(acc[2][rr] + __half2float(xh[2][rr]));
      float ov = sigm(acc[3][rr] + __half2float(xh[3][rr]));
      float c = fmaf(fv, c0[rr], iv * gv);
      c0[rr] = c;
      float hv = ov * tanha(c);
      __half hh = __float2half(hv);
      int m = (q << 2) + rr;
      hout[((size_t)(((g << 4) + m) * TCH + tl) << 8) + nbase] = hh;
      unsigned hu = (unsigned)__half_as_ushort(hh);
      unsigned ot = (unsigned)__shfl_xor((int)hu, 1);
      prv[rr] = (ot << 16) | hu;        // valid on even-r lanes
    }
    // even-r lanes: write own-frag region + publish to partner
    if (!(r & 1)) {
      unsigned long long tg = ((unsigned long long)(unsigned)(t + 1)) << 32;
      unsigned long long* dstb = exA + ((size_t)((t + 1) & 1) << 10);
#pragma unroll
      for (int rr = 0; rr < 4; ++rr) {
        int m = (q << 2) + rr;
        // own-frag u32 idx: s=w>>1, b=2*(w&1)+(r>>3), e=(r&7)>>1
        h1w[((w >> 1) << 8) + ((((w & 1) << 1) | (r >> 3)) << 6) + (m << 2) + ((r & 7) >> 1)] = prv[rr];
        int widx = (m << 6) + (w << 3) + (r >> 1);
        __hip_atomic_store(dstb + widx, tg | (unsigned long long)prv[rr],
                           __ATOMIC_RELAXED, __HIP_MEMORY_SCOPE_AGENT);
      }
    }
    // speculative partner loads for step t+1
    if (t + 1 < tend) {
      const unsigned long long* pb = exB + ((size_t)((t + 1) & 1) << 10) + widx0;
      pw[0] = __hip_atomic_load(pb, __ATOMIC_RELAXED, __HIP_MEMORY_SCOPE_AGENT);
      pw[1] = __hip_atomic_load(pb + 1, __ATOMIC_RELAXED, __HIP_MEMORY_SCOPE_AGENT);
    }
    __syncthreads();      // own-frag region now h_{t+1}
  }

  // carry state across chunks
  if (tid < 256)
    ((uint4*)(hsave + ((size_t)sid << 11)))[tid] = ((const uint4*)hfr)[tid];
  {
    int i = (w << 4) + r;
#pragma unroll
    for (int rr = 0; rr < 4; ++rr)
      csave[((size_t)sid << 11) + (i << 4) + (q << 2) + rr] = c0[rr];
  }
}

// ---------------- head: decision = h2 . Wd + bd, ragged-masked sum, final /len
__global__ __launch_bounds__(256, 2) void head_k(
    const __half* __restrict__ h2, const float* __restrict__ Wd,
    const float* __restrict__ bd, const int* __restrict__ length,
    float* __restrict__ dacc, float* __restrict__ out, int t0, int first, int last)
{
  int b = blockIdx.x, tid = threadIdx.x;
  int lane = tid & 63, wave = tid >> 6;
  int len = length[b];
  int tend = min(t0 + TCH, len);
  float4 w4 = *(const float4*)(Wd + (lane << 2));
  float wsum = 0.f;
  for (int t = t0 + wave; t < tend; t += 4) {
    const __half* hr = h2 + (((size_t)b * TCH) + (t - t0)) * 256 + (lane << 2);
    uint2 u = *(const uint2*)hr;
    __half2 p0 = __builtin_bit_cast(__half2, u.x);
    __half2 p1 = __builtin_bit_cast(__half2, u.y);
    float s = w4.x * __half2float(p0.x) + w4.y * __half2float(p0.y)
            + w4.z * __half2float(p1.x) + w4.w * __half2float(p1.y);
#pragma unroll
    for (int off = 32; off > 0; off >>= 1) s += __shfl_xor(s, off);
    wsum += s;    // s is full-wave sum, counted once via lane0 below
  }
  __shared__ float wred[4];
  if (lane == 0) wred[wave] = wsum;
  __syncthreads();
  if (tid == 0) {
    int cnt = tend - t0; if (cnt < 0) cnt = 0;
    float tot = wred[0] + wred[1] + wred[2] + wred[3] + bd[0] * (float)cnt;
    if (!first) tot += dacc[b];
    dacc[b] = tot;
    if (last) out[b] = tot / (float)len;
  }
}

extern "C" void kernel_launch(void* const* d_in, const int* in_sizes, int n_in,
                              void* d_out, int out_size, void* d_ws, size_t ws_size,
                              hipStream_t stream) {
  (void)in_sizes; (void)n_in; (void)out_size; (void)ws_size;
  const float* x    = (const float*)d_in[0];
  const int* length = (const int*)d_in[1];
  const float* W1   = (const float*)d_in[2];
  const float* b1   = (const float*)d_in[3];
  const float* W2   = (const float*)d_in[4];
  const float* b2   = (const float*)d_in[5];
  const float* wih[3] = {(const float*)d_in[6],  (const float*)d_in[10], (const float*)d_in[14]};
  const float* whh[3] = {(const float*)d_in[7],  (const float*)d_in[11], (const float*)d_in[15]};
  const float* bih[3] = {(const float*)d_in[8],  (const float*)d_in[12], (const float*)d_in[16]};
  const float* bhh[3] = {(const float*)d_in[9],  (const float*)d_in[13], (const float*)d_in[17]};
  const float* Wd   = (const float*)d_in[18];
  const float* bd   = (const float*)d_in[19];
  float* out = (float*)d_out;

  char* ws = (char*)d_ws;
  __half* XG    = (__half*)(ws);                     // 32768 x 1024 f16 = 64 MiB
  __half* FEAT2 = (__half*)(ws + 67108864);          // 32768 x 512  f16 = 32 MiB
  __half* FEAT1 = (__half*)(ws + 100663296);         // 32768 x 256  f16 = 16 MiB
  __half* HBUF  = FEAT1;                             // aliased: F1 dead before scan writes
  __half* WPK   = (__half*)(ws + 117440512);         // 3 x 512 KiB packed W_hh frags
  __half* HSV   = (__half*)(ws + 119013376);         // 3 x 64 KiB h state (frag order)
  float*  CSV   = (float*)(ws + 119209984);          // 3 x 128 KiB c state
  unsigned long long* EXC = (unsigned long long*)(ws + 119603200);  // 3 x 256 KiB exchange
  float* DACC   = (float*)(ws + 120389632);

  // pack recurrent weights into MFMA B-frag order (cheap, idempotent)
  for (int l = 0; l < 3; ++l)
    pack_whh<<<512, 64, 0, stream>>>(whh[l], WPK + (size_t)l * 262144);

  for (int c = 0; c < NCH; ++c) {
    int t0 = c * TCH;
    // MLP1: x[.,136] -> 256, relu
    gemm_k<true,  true ><<<dim3(256, 2), 256, 0, stream>>>(
        (const void*)(x + (size_t)t0 * 136), W1, b1, FEAT1, length, 136, 5, 256, 1024, t0);
    // MLP2: 256 -> 512, relu
    gemm_k<false, true ><<<dim3(256, 4), 256, 0, stream>>>(
        (const void*)FEAT1, W2, b2, FEAT2, length, 256, 8, 512, TCH, t0);
    // layer 0
    gemm_k<false, false><<<dim3(256, 8), 256, 0, stream>>>(
        (const void*)FEAT2, wih[0], nullptr, XG, length, 512, 16, 1024, TCH, t0);
    scan_mf<<<16, 512, 0, stream>>>(XG, WPK, bih[0], bhh[0], HBUF,
                                    HSV, CSV, EXC, length, t0);
    // layer 1
    gemm_k<false, false><<<dim3(256, 8), 256, 0, stream>>>(
        (const void*)HBUF, wih[1], nullptr, XG, length, 256, 8, 1024, TCH, t0);
    scan_mf<<<16, 512, 0, stream>>>(XG, WPK + 262144, bih[1], bhh[1], HBUF,
                                    HSV + 32768, CSV + 32768, EXC + 32768, length, t0);
    // layer 2
    gemm_k<false, false><<<dim3(256, 8), 256, 0, stream>>>(
        (const void*)HBUF, wih[2], nullptr, XG, length, 256, 8, 1024, TCH, t0);
    scan_mf<<<16, 512, 0, stream>>>(XG, WPK + 524288, bih[2], bhh[2], HBUF,
                                    HSV + 65536, CSV + 65536, EXC + 65536, length, t0);
    // head + ragged mean
    head_k<<<128, 256, 0, stream>>>(HBUF, Wd, bd, length, DACC, out, t0, c == 0, c == NCH - 1);
  }
}